// Round 2
// baseline (587.832 us; speedup 1.0000x reference)
//
#include <hip/hip_runtime.h>
#include <math.h>

// DiffDispatchLP: batched (256x) PDHG, 400 iters. One WG per batch item.
// Fully analytic structure: phase A (x-update, K^T gather) specialized per
// variable type (waves are type-pure since columns are contiguous in tid);
// phase B (y-update, K gather) specialized per constraint family with
// shared x_bar reads and consecutive dual writes (ds_read2/write2 friendly).
// Power iteration (40 steps) for ||K||_2 reuses the same code via POWER flag.

#define NITER 400
#define PITER 40

// min-duration row offset within its v-block; valid t in [0,94], k in 1..3
__device__ __forceinline__ int mrow(int t, int k) {
  return (t <= 92) ? (3 * t + k - 1) : ((t == 93) ? (278 + k) : 281);
}

// ---------------- phase A gathers: g = (K^T y)[col] ----------------

__device__ __forceinline__ float gather_c(const float* sy, int t, float cET) {
  const float* br = sy + 97 + 13 * t;
  float g = cET * sy[t] + br[0] - br[2] + br[11] + 0.25f * sy[2479];
  int tm = (t >= 1) ? (t - 1) : 0;
  const float* rl = sy + 1345 + 4 * tm;  // ramp rows R(t)
  const float* rr = sy + 1345 + 4 * t;   // ramp rows R(t+1)
  float gl = rl[0] - rl[1];
  float gr = rr[1] - rr[0];
  if (t >= 1)  g += gl;
  if (t <= 94) g += gr;
  return g;
}

__device__ __forceinline__ float gather_d(const float* sy, int t, float cDE) {
  const float* br = sy + 97 + 13 * t;
  float g = cDE * sy[t] + br[1] - br[3] + br[12];
  int tm = (t >= 1) ? (t - 1) : 0;
  const float* rl = sy + 1345 + 4 * tm;
  const float* rr = sy + 1345 + 4 * t;
  float gl = rl[2] - rl[3];
  float gr = rr[3] - rr[2];
  if (t >= 1)  g += gl;
  if (t <= 94) g += gr;
  return g;
}

__device__ __forceinline__ float gather_y(const float* sy, int v, int t) {
  const float* br = sy + 97 + 13 * t;
  float g = -br[4 + 2 * v] + br[5 + 2 * v] + br[10] - 195.0f * br[11 + v];
  int tm = (t >= 1) ? (t - 1) : 0;
  float s0 = sy[1725 + 2 * t + v];        // S(t), masked for t=95 (reads valid LDS)
  float s1 = sy[1725 + 2 * tm + 1 - v];   // S(t-1)
  if (t <= 94) g += s0;
  if (t >= 1)  g += s1;
  const float* md = sy + 1915 + 282 * v;
  int ta = (t <= 94) ? t : 94;
  int tb = (t <= 93) ? (t + 1) : 94;
#pragma unroll
  for (int k = 1; k <= 3; ++k) {
    int tbk = (t >= k) ? (t - k) : 0;
    float own  = md[mrow(ta, k)];
    float back = md[mrow(tbk, k)];
    float frnt = md[mrow(tb, k)];
    if (k <= 95 - t) g += own;   // +1 in own rows (t,k)
    if (k <= t)      g -= back;  // -1 as y_{t'+k} in rows (t-k,k)
    if (k <= 94 - t) g -= frnt;  // -1 as y_{t'-1} in rows (t+1,k)
  }
  return g;
}

__device__ __forceinline__ float gather_s(const float* sy, int t) {
  const float* br = sy + 97 + 13 * t;
  float g = sy[t] - br[8] + br[9];
  float nxt = sy[t + 1];            // t=95: sy[96] with +1 (row 96: soc_95 = 0)
  g += (t <= 94) ? (-nxt) : nxt;
  return g;
}

// ---------------- phase B row update helper ----------------

template<bool POWER>
__device__ __forceinline__ void upd(float* wrow, int j, float dot, float rhs,
                                    bool proj, float& yreg, float sig, bool wr = true) {
  if (POWER) {
    if (wr) wrow[j] = dot;
  } else {
    float yn = yreg + sig * (dot - rhs);
    if (proj) yn = fmaxf(yn, 0.0f);
    if (wr) { yreg = yn; wrow[j] = yn; }
  }
}

// box: 13 rows at t; reads 5 x_bar, writes 13 consecutive duals
template<bool POWER>
__device__ __forceinline__ void taskB(const float* sxb, float* sy, int t, float sig, float* y) {
  float c  = sxb[t];
  float d  = sxb[96 + t];
  float yc = sxb[192 + t];
  float yd = sxb[288 + t];
  float s  = sxb[384 + t];
  float* w = sy + 97 + 13 * t;
  upd<POWER>(w, 0,  c,              195.0f, true, y[0],  sig);
  upd<POWER>(w, 1,  d,              195.0f, true, y[1],  sig);
  upd<POWER>(w, 2, -c,              0.0f,   true, y[2],  sig);
  upd<POWER>(w, 3, -d,              0.0f,   true, y[3],  sig);
  upd<POWER>(w, 4, -yc,             0.0f,   true, y[4],  sig);
  upd<POWER>(w, 5,  yc,             1.0f,   true, y[5],  sig);
  upd<POWER>(w, 6, -yd,             0.0f,   true, y[6],  sig);
  upd<POWER>(w, 7,  yd,             1.0f,   true, y[7],  sig);
  upd<POWER>(w, 8, -s,              0.0f,   true, y[8],  sig);
  upd<POWER>(w, 9,  s,              800.0f, true, y[9],  sig);
  upd<POWER>(w,10,  yc + yd,        1.0f,   true, y[10], sig);
  upd<POWER>(w,11,  c - 195.0f*yc,  0.0f,   true, y[11], sig);
  upd<POWER>(w,12,  d - 195.0f*yd,  0.0f,   true, y[12], sig);
}

// equality row t (0..96); no projection
template<bool POWER>
__device__ __forceinline__ void taskE(const float* sxb, float* sy, int t, float sig,
                                      float& y, float cET, float cDE) {
  float dot;
  if (t == 96) {
    dot = sxb[384 + 95];
  } else {
    int tm = (t >= 1) ? (t - 1) : 0;
    float sm = sxb[384 + tm];
    dot = sxb[384 + t] + cET * sxb[t] + cDE * sxb[96 + t];
    if (t >= 1) dot -= sm;
  }
  upd<POWER>(sy, t, dot, 0.0f, false, y, sig);
}

// ramp: 4 rows at t (1..95)
template<bool POWER>
__device__ __forceinline__ void taskR(const float* sxb, float* sy, int t, float sig, float* y) {
  float cm = sxb[t - 1],       c0 = sxb[t];
  float dm = sxb[96 + t - 1],  d0 = sxb[96 + t];
  float* w = sy + 1345 + 4 * (t - 1);
  upd<POWER>(w, 0, c0 - cm, 65.0f, true, y[0], sig);
  upd<POWER>(w, 1, cm - c0, 65.0f, true, y[1], sig);
  upd<POWER>(w, 2, d0 - dm, 65.0f, true, y[2], sig);
  upd<POWER>(w, 3, dm - d0, 65.0f, true, y[3], sig);
}

// switch: 2 rows at t (0..94)
template<bool POWER>
__device__ __forceinline__ void taskS(const float* sxb, float* sy, int t, float sig, float* y) {
  float a0 = sxb[192 + t], a1 = sxb[192 + t + 1];
  float b0 = sxb[288 + t], b1 = sxb[288 + t + 1];
  float* w = sy + 1725 + 2 * t;
  upd<POWER>(w, 0, a0 + b1, 1.0f, true, y[0], sig);
  upd<POWER>(w, 1, b0 + a1, 1.0f, true, y[1], sig);
}

// min-duration: up to 3 rows at (v,t), t in 0..94
template<bool POWER>
__device__ __forceinline__ void taskM(const float* sxb, float* sy, int v, int t, float sig, float* y) {
  int bc = 192 + 96 * v;
  int mb = 1915 + 282 * v;
  float yt = sxb[bc + t];
  int tmm = (t >= 1) ? (t - 1) : 0;
  float ytm = sxb[bc + tmm];
  float base = yt - ((t >= 1) ? ytm : 0.0f);
#pragma unroll
  for (int k = 1; k <= 3; ++k) {
    int tk = t + k; if (tk > 95) tk = 95;
    float ya = sxb[bc + tk];
    bool ex = (t + k <= 95);
    upd<POWER>(sy + mb, mrow(t, k), base - ya, 0.0f, true, y[k - 1], sig, ex);
  }
}

// phase B: apply K (POWER) or full dual update (PDHG). Covers all 2480 rows.
template<bool POWER>
__device__ __forceinline__ void phaseB_run(int lane, int wid, const float* sxb, float* sy,
                                           float sig, float* y1, float* y2, float* y3,
                                           float& ytc, float cET, float cDE) {
  // slot 1: box(96) + eq(97) + ramp(1..63)
  if (wid == 0) {
    taskB<POWER>(sxb, sy, lane, sig, y1);
  } else if (wid == 1) {
    if (lane < 32) taskB<POWER>(sxb, sy, 64 + lane, sig, y1);
    else           taskE<POWER>(sxb, sy, lane - 32, sig, y1[0], cET, cDE);
  } else if (wid == 2) {
    taskE<POWER>(sxb, sy, 32 + lane, sig, y1[0], cET, cDE);
  } else {
    if (lane == 0) taskE<POWER>(sxb, sy, 96, sig, y1[0], cET, cDE);
    else           taskR<POWER>(sxb, sy, lane, sig, y1);
  }
  // slot 2: ramp(64..95) + switch(95) + mindur(yc all, yd 0..33)
  if (wid == 0) {
    if (lane < 32) taskR<POWER>(sxb, sy, 64 + lane, sig, y2);
    else           taskS<POWER>(sxb, sy, lane - 32, sig, y2);
  } else if (wid == 1) {
    if (lane < 63) taskS<POWER>(sxb, sy, 32 + lane, sig, y2);
    else           taskM<POWER>(sxb, sy, 0, 0, sig, y2);
  } else if (wid == 2) {
    taskM<POWER>(sxb, sy, 0, 1 + lane, sig, y2);
  } else {
    int v = (lane < 30) ? 0 : 1;
    int t = (lane < 30) ? (65 + lane) : (lane - 30);
    taskM<POWER>(sxb, sy, v, t, sig, y2);
  }
  // slot 3: mindur(yd 34..94) on wid0; total-charge reduce on wid2
  if (wid == 0) {
    if (lane < 61) taskM<POWER>(sxb, sy, 1, 34 + lane, sig, y3);
  } else if (wid == 2) {
    float s = sxb[lane] + ((lane < 32) ? sxb[64 + lane] : 0.0f);
#pragma unroll
    for (int m = 32; m >= 1; m >>= 1) s += __shfl_xor(s, m, 64);
    if (lane == 0) {
      if (POWER) {
        sy[2479] = 0.25f * s;
      } else {
        float yn = ytc + sig * (0.25f * s - 1200.0f);
        ytc = fmaxf(yn, 0.0f);
        sy[2479] = ytc;
      }
    }
  }
}

// phase A gather for this thread's two columns (colA = tid, colB = 256+tid)
#define GATHER(gA, gB) do {                                                            \
  if (wid == 0)      gA = gather_c(sy, lane, cET);                                     \
  else if (wid == 1) gA = (lane < 32) ? gather_c(sy, 64 + lane, cET)                   \
                                      : gather_d(sy, lane - 32, cDE);                  \
  else if (wid == 2) gA = gather_d(sy, 32 + lane, cDE);                                \
  else               gA = gather_y(sy, 0, lane);                                       \
  if (wid == 0)      gB = gather_y(sy, (lane < 32) ? 0 : 1,                            \
                                   (lane < 32) ? (64 + lane) : (lane - 32));           \
  else if (wid == 1) gB = gather_y(sy, 1, 32 + lane);                                  \
  else if (wid == 2) gB = gather_s(sy, lane);                                          \
  else               gB = (lane < 32) ? gather_s(sy, 64 + lane) : 0.0f;                \
} while (0)

__global__ __launch_bounds__(256, 1)
void lp_solve_kernel(const float* __restrict__ price, float* __restrict__ out) {
  __shared__ float sy[2480];   // duals / K*v
  __shared__ float sxb[480];   // x_bar / power vector
  __shared__ float s_red[4];

  const int tid  = threadIdx.x;
  const int lane = tid & 63;
  const int wid  = tid >> 6;
  const int bi   = blockIdx.x;

  const double ETA_D = sqrt(0.91);
  const float cET = (float)(-(ETA_D * 0.25));  // -ETA*DT
  const float cDE = (float)(0.25 / ETA_D);     // DT/ETA

  float y1[13], y2[4], y3[3], ytc = 0.0f;

  // ---------------- power iteration: lam2 -> ||K||_2^2 ----------------
  sxb[tid] = 1.0f;
  if (tid < 224) sxb[256 + tid] = 1.0f;
  __syncthreads();

  float lam2 = 1.0f;
  for (int pit = 0; pit < PITER; ++pit) {
    phaseB_run<true>(lane, wid, sxb, sy, 0.0f, y1, y2, y3, ytc, cET, cDE);
    __syncthreads();
    float gA, gB = 0.0f;
    GATHER(gA, gB);
    float part = gA * gA + gB * gB;
#pragma unroll
    for (int m = 32; m >= 1; m >>= 1) part += __shfl_xor(part, m, 64);
    if (lane == 0) s_red[wid] = part;
    __syncthreads();
    float nrm = s_red[0] + s_red[1] + s_red[2] + s_red[3];
    lam2 = sqrtf(nrm);
    float inv = 1.0f / lam2;
    sxb[tid] = gA * inv;
    if (tid < 224) sxb[256 + tid] = gB * inv;
    __syncthreads();
  }
  const float tau = (float)(0.9 / sqrt((double)lam2));
  const float sig = tau;

  // ---------------- init PDHG state ----------------
  for (int i = tid; i < 2480; i += 256) sy[i] = 0.0f;
  float qA = 0.0f;
  if (tid < 96)       qA =  0.25f * price[bi * 96 + tid];
  else if (tid < 192) qA = -0.25f * price[bi * 96 + (tid - 96)];
  float xA = 0.0f, xB = 0.0f;
#pragma unroll
  for (int j = 0; j < 13; ++j) y1[j] = 0.0f;
#pragma unroll
  for (int j = 0; j < 4; ++j)  y2[j] = 0.0f;
#pragma unroll
  for (int j = 0; j < 3; ++j)  y3[j] = 0.0f;
  ytc = 0.0f;
  __syncthreads();

  // ---------------- 400 PDHG iterations ----------------
#pragma unroll 1
  for (int it = 0; it < NITER; ++it) {
    float gA, gB = 0.0f;
    GATHER(gA, gB);
    float xa = xA - tau * (qA + gA);
    sxb[tid] = 2.0f * xa - xA;
    xA = xa;
    if (tid < 224) {
      float xb = xB - tau * gB;
      sxb[256 + tid] = 2.0f * xb - xB;
      xB = xb;
    }
    __syncthreads();
    phaseB_run<false>(lane, wid, sxb, sy, sig, y1, y2, y3, ytc, cET, cDE);
    __syncthreads();
  }

  // ---------------- output: c then d, each (256,96) ----------------
  if (wid == 0) {
    out[bi * 96 + lane] = xA;
  } else if (wid == 1) {
    if (lane < 32) out[bi * 96 + 64 + lane] = xA;
    else           out[24576 + bi * 96 + (lane - 32)] = xA;
  } else if (wid == 2) {
    out[24576 + bi * 96 + 32 + lane] = xA;
  }
}

extern "C" void kernel_launch(void* const* d_in, const int* in_sizes, int n_in,
                              void* d_out, int out_size, void* d_ws, size_t ws_size,
                              hipStream_t stream) {
  const float* price = (const float*)d_in[0];
  float* out = (float*)d_out;
  hipLaunchKernelGGL(lp_solve_kernel, dim3(256), dim3(256), 0, stream, price, out);
}

// Round 3
// 358.723 us; speedup vs baseline: 1.6387x; 1.6387x over previous
//
#include <hip/hip_runtime.h>
#include <math.h>

// DiffDispatchLP: batched (256x) PDHG, 400 iters, one WG (4 waves) per item.
// SoA dual layout in LDS (all lane accesses stride-1, read2/write2-mergeable),
// all addresses/masks precomputed into registers before the iteration loop,
// per-wave uniform task bodies (c/d and yc/yd unified via register bases).

#define NITER 400
#define PITER 10

// dual-vector LDS layout (dword offsets)
#define EQO   0      // eq[97]
#define BOXO  97     // box[13][96]
#define RAMPO 1345   // ramp[4][95], row t(1..95) at t-1
#define SWO   1725   // sw[2][95], t=0..94
#define MDO   1915   // md[v][k][95]: MDO + 285v + 95(k-1)
#define TCO   2485
#define NY    2488

__global__ __launch_bounds__(256, 1)
void lp_solve_kernel(const float* __restrict__ price, float* __restrict__ out) {
  __shared__ float sy[NY];     // duals / K*v
  __shared__ float sxb[488];   // x_bar (SoA: c0 d96 yc192 yd288 soc384) / power v
  __shared__ float s_red[4];

  const int tid = threadIdx.x, lane = tid & 63, wid = tid >> 6, bi = blockIdx.x;
  const double ETA_D = sqrt(0.91);
  const float cET = (float)(-(ETA_D * 0.25));  // -ETA*DT
  const float cDE = (float)(0.25 / ETA_D);     // DT/ETA

  // ============ phase A precompute (columns) ============
  // colA: tid<192 -> c/d column; w3 -> yc[lane]
  const int   cdv = (tid >= 96) ? 1 : 0;
  const int   tcd = (tid < 192) ? (tid - 96 * cdv) : lane;
  const int   aEq = EQO + tcd;
  const int   aB0 = BOXO + 96 * cdv + tcd;            // +0: box[j0], +192: box[j0+2]
  const int   aB3 = BOXO + 96 * (11 + cdv) + tcd;
  const int   aRm = RAMPO + 190 * cdv + ((tcd >= 1) ? tcd - 1 : 0);   // +0 up, +95 down (row t)
  const int   aRp = RAMPO + 190 * cdv + ((tcd <= 94) ? tcd : 94);     // row t+1
  const float ce  = cdv ? cDE : cET;
  const float cmm = (tcd >= 1) ? 1.f : 0.f;
  const float cpp = (tcd <= 94) ? 1.f : 0.f;
  const float ctc = cdv ? 0.f : 0.25f;

  // y-column (yc/yd): w0 colB, w1 colB, w3 colA
  int yv, yt;
  if (wid == 0)      { yv = (lane < 32) ? 0 : 1; yt = (lane < 32) ? 64 + lane : lane - 32; }
  else if (wid == 1) { yv = 1; yt = 32 + lane; }
  else               { yv = 0; yt = lane; }   // used by wid==3
  const int   aB45 = BOXO + 96 * (4 + 2 * yv) + yt;   // +0: box[4+2v], +96: box[5+2v]
  const int   aB10 = BOXO + 960 + yt;
  const int   aB11 = BOXO + 96 * (11 + yv) + yt;
  const int   aSw0 = SWO + 95 * yv + ((yt <= 94) ? yt : 94);
  const int   aSw1 = SWO + 95 * (1 - yv) + ((yt >= 1) ? yt - 1 : 0);
  const float cs0 = (yt <= 94) ? 1.f : 0.f;
  const float cs1 = (yt >= 1) ? 1.f : 0.f;
  const int   mvb = MDO + 285 * yv;
  const int   aOwn = mvb + ((yt <= 94) ? yt : 94);    // +0,+95,+190 : k=1,2,3 at t
  const float co1 = (yt <= 94) ? 1.f : 0.f;
  const float co2 = (yt <= 93) ? 1.f : 0.f;
  const float co3 = (yt <= 92) ? 1.f : 0.f;
  const int   aK1 = mvb + ((yt >= 1) ? yt - 1 : 0);
  const int   aK2 = mvb + 95 + ((yt >= 2) ? yt - 2 : 0);
  const int   aK3 = mvb + 190 + ((yt >= 3) ? yt - 3 : 0);
  const float cb1 = (yt >= 1) ? 1.f : 0.f;
  const float cb2 = (yt >= 2) ? 1.f : 0.f;
  const float cb3 = (yt >= 3) ? 1.f : 0.f;
  const int   aFr = mvb + ((yt <= 94) ? yt + 1 : 94); // rows (t+1,k)
  const float cf1 = (yt <= 93) ? 1.f : 0.f;
  const float cf2 = (yt <= 92) ? 1.f : 0.f;
  const float cf3 = (yt <= 91) ? 1.f : 0.f;

  // soc column: w2 colB (t=lane), w3 colB (t=64+lane, lane<32)
  const bool  sActB = (wid == 2) || (lane < 32);
  const int   st0 = (wid == 2) ? lane : (sActB ? 64 + lane : 95);
  const int   aSE = EQO + st0;                        // +0: eq[t], +1: eq[t+1]
  const float ce1 = (st0 <= 94) ? -1.f : 1.f;         // t=95: +eq[96]
  const int   aSB = BOXO + 768 + st0;                 // +0: box8, +96: box9

  const int wxA = (wid < 3) ? tid : (192 + lane);
  int wxB;
  if (wid == 0)      wxB = 192 + 96 * yv + yt;
  else if (wid == 1) wxB = 288 + yt;
  else               wxB = 384 + st0;
  const bool wBact = (wid < 3) || (lane < 32);

  // ============ phase B precompute (rows) ============
  // BOX: w0 t=lane, w1 t=64+lane (lane<32)
  const bool bAct = (wid == 0) || (lane < 32);
  const int  tb   = (wid == 0) ? lane : (bAct ? 64 + lane : 95);
  const int  aXcd = tb, aXy = 192 + tb, aXs = 384 + tb;
  const int  wBx  = BOXO + tb;
  // MD: w0 idx lane, w1 64+lane, w2 128+lane (<190)
  const int  mi0  = (wid == 0) ? lane : (wid == 1) ? 64 + lane : 128 + lane;
  const bool mAct = (wid < 3) && (mi0 < 190);
  const int  mi   = mAct ? mi0 : 189;
  const int  mdv  = mi / 95, mdt = mi % 95;
  const int  mxb2 = 192 + 96 * mdv;
  const int  aMp  = mxb2 + ((mdt >= 1) ? mdt - 1 : 0);
  const int  aMc  = mxb2 + mdt;                        // +1 = y[t+1]
  const int  aM2  = mxb2 + ((mdt <= 93) ? mdt + 2 : 95);
  const int  aM3  = mxb2 + ((mdt <= 92) ? mdt + 3 : 95);
  const float cMp = (mdt >= 1) ? 1.f : 0.f;
  const int  wMd  = MDO + 285 * mdv + mdt;
  const bool vM1 = mAct, vM2 = mAct && (mdt <= 93), vM3 = mAct && (mdt <= 92);
  // RAMP: w2 tr=1+lane, w3 tr=65+lane (lane<31)
  const bool rAct = (wid == 2) || (lane < 31);
  const int  tr   = (wid == 2) ? 1 + lane : (rAct ? 65 + lane : 95);
  const int  aRc  = tr - 1, aRd = 96 + tr - 1;        // +0,+1
  const int  wR   = RAMPO + tr - 1;                    // +0,+95,+190,+285
  // SW: w2 t=lane, w3 t=64+lane (lane<31)
  const bool swAct = (wid == 2) || (lane < 31);
  const int  tsw  = (wid == 2) ? lane : (swAct ? 64 + lane : 94);
  const int  aSwc = 192 + tsw, aSwd = 288 + tsw;       // +0,+1
  const int  wS   = SWO + tsw;                          // +0,+95
  // EQ: w3 r=lane, w2 r=64+lane (lane<33)
  const bool eAct = (wid == 3) || (lane < 33);
  const int  er   = (wid == 3) ? lane : (eAct ? 64 + lane : 96);
  const int  ete  = (er <= 95) ? er : 95;
  const int  aEp  = 384 + ((ete >= 1) ? ete - 1 : 0);
  const int  aEc  = 384 + ete;
  const int  aEx  = ete;                                // +0 xc, +96 xd
  const float cEb = (er >= 1 && er <= 95) ? 1.f : 0.f;
  const float cEm = (er <= 95) ? 1.f : 0.f;
  const int  wE   = EQO + er;

  // ============ state ============
  float xA = 0.f, xB = 0.f, qA = 0.f;
  float yb0=0,yb1=0,yb2=0,yb3=0,yb4=0,yb5=0,yb6=0,yb7=0,yb8=0,yb9=0,yb10=0,yb11=0,yb12=0;
  float ym1=0, ym2=0, ym3=0;
  float yr0=0, yr1=0, yr2=0, yr3=0;
  float ysw0=0, ysw1=0, yeq=0, ytc=0;
  float tau = 0.f, sig = 0.f;

  auto gatherA = [&](float& gA, float& gB) {
    float gCD = 0.f, gY = 0.f, gS = 0.f;
    if (wid < 3) {
      float e   = sy[aEq];
      float blo = sy[aB0], bhi = sy[aB0 + 192];
      float b3  = sy[aB3];
      float rp0 = sy[aRm], rq0 = sy[aRm + 95];
      float rp1 = sy[aRp], rq1 = sy[aRp + 95];
      float tcv = sy[TCO];
      gCD = ce * e + (blo - bhi) + b3 + cmm * (rp0 - rq0) + cpp * (rq1 - rp1) + ctc * tcv;
    }
    if (wid != 2) {
      float b4 = sy[aB45], b5 = sy[aB45 + 96];
      float b10 = sy[aB10], b11 = sy[aB11];
      float s0 = sy[aSw0], s1 = sy[aSw1];
      float o1 = sy[aOwn], o2 = sy[aOwn + 95], o3 = sy[aOwn + 190];
      float k1 = sy[aK1], k2 = sy[aK2], k3 = sy[aK3];
      float f1 = sy[aFr], f2 = sy[aFr + 95], f3 = sy[aFr + 190];
      gY = -b4 + b5 + b10 - 195.f * b11 + cs0 * s0 + cs1 * s1
         + co1 * o1 + co2 * o2 + co3 * o3
         - (cb1 * k1 + cb2 * k2 + cb3 * k3)
         - (cf1 * f1 + cf2 * f2 + cf3 * f3);
    }
    if (wid >= 2) {
      float e0 = sy[aSE], e1n = sy[aSE + 1];
      float b8 = sy[aSB], b9 = sy[aSB + 96];
      gS = e0 + ce1 * e1n - b8 + b9;
    }
    gA = (wid < 3) ? gCD : gY;
    gB = (wid < 2) ? gY : gS;
  };

  auto phaseB = [&](bool power) {
    if (wid < 2) {
      // BOX: 13 rows at tb
      float c_ = sxb[aXcd], d_ = sxb[aXcd + 96];
      float yc_ = sxb[aXy], yd_ = sxb[aXy + 96];
      float s_ = sxb[aXs];
      float v0,v1,v2,v3,v4,v5,v6,v7,v8,v9,v10,v11,v12;
      if (power) {
        v0=c_; v1=d_; v2=-c_; v3=-d_; v4=-yc_; v5=yc_; v6=-yd_; v7=yd_;
        v8=-s_; v9=s_; v10=yc_+yd_; v11=c_-195.f*yc_; v12=d_-195.f*yd_;
      } else {
        yb0  = fmaxf(yb0  + sig*(c_  - 195.f), 0.f);       v0 = yb0;
        yb1  = fmaxf(yb1  + sig*(d_  - 195.f), 0.f);       v1 = yb1;
        yb2  = fmaxf(yb2  + sig*(-c_),         0.f);       v2 = yb2;
        yb3  = fmaxf(yb3  + sig*(-d_),         0.f);       v3 = yb3;
        yb4  = fmaxf(yb4  + sig*(-yc_),        0.f);       v4 = yb4;
        yb5  = fmaxf(yb5  + sig*(yc_ - 1.f),   0.f);       v5 = yb5;
        yb6  = fmaxf(yb6  + sig*(-yd_),        0.f);       v6 = yb6;
        yb7  = fmaxf(yb7  + sig*(yd_ - 1.f),   0.f);       v7 = yb7;
        yb8  = fmaxf(yb8  + sig*(-s_),         0.f);       v8 = yb8;
        yb9  = fmaxf(yb9  + sig*(s_ - 800.f),  0.f);       v9 = yb9;
        yb10 = fmaxf(yb10 + sig*(yc_ + yd_ - 1.f), 0.f);   v10 = yb10;
        yb11 = fmaxf(yb11 + sig*(c_ - 195.f*yc_), 0.f);    v11 = yb11;
        yb12 = fmaxf(yb12 + sig*(d_ - 195.f*yd_), 0.f);    v12 = yb12;
      }
      if (bAct) {
        sy[wBx]        = v0;  sy[wBx + 96]   = v1;  sy[wBx + 192]  = v2;
        sy[wBx + 288]  = v3;  sy[wBx + 384]  = v4;  sy[wBx + 480]  = v5;
        sy[wBx + 576]  = v6;  sy[wBx + 672]  = v7;  sy[wBx + 768]  = v8;
        sy[wBx + 864]  = v9;  sy[wBx + 960]  = v10; sy[wBx + 1056] = v11;
        sy[wBx + 1152] = v12;
      }
    }
    if (wid < 3) {
      // MD: rows (mdv, k=1..3, mdt)
      float mp = sxb[aMp];
      float mc = sxb[aMc], m1v = sxb[aMc + 1];
      float m2v = sxb[aM2], m3v = sxb[aM3];
      float mbase = mc - cMp * mp;
      float d1 = mbase - m1v, d2 = mbase - m2v, d3 = mbase - m3v;
      float o1w, o2w, o3w;
      if (power) { o1w = d1; o2w = d2; o3w = d3; }
      else {
        ym1 = fmaxf(ym1 + sig * d1, 0.f); o1w = ym1;
        ym2 = fmaxf(ym2 + sig * d2, 0.f); o2w = ym2;
        ym3 = fmaxf(ym3 + sig * d3, 0.f); o3w = ym3;
      }
      if (vM1) sy[wMd]       = o1w;
      if (vM2) sy[wMd + 95]  = o2w;
      if (vM3) sy[wMd + 190] = o3w;
    }
    if (wid >= 2) {
      // RAMP: 4 rows at tr
      float rcm = sxb[aRc], rc0 = sxb[aRc + 1];
      float rdm = sxb[aRd], rd0 = sxb[aRd + 1];
      float u0, u1, u2, u3;
      if (power) { u0 = rc0 - rcm; u1 = rcm - rc0; u2 = rd0 - rdm; u3 = rdm - rd0; }
      else {
        yr0 = fmaxf(yr0 + sig * (rc0 - rcm - 65.f), 0.f); u0 = yr0;
        yr1 = fmaxf(yr1 + sig * (rcm - rc0 - 65.f), 0.f); u1 = yr1;
        yr2 = fmaxf(yr2 + sig * (rd0 - rdm - 65.f), 0.f); u2 = yr2;
        yr3 = fmaxf(yr3 + sig * (rdm - rd0 - 65.f), 0.f); u3 = yr3;
      }
      if (rAct) { sy[wR] = u0; sy[wR + 95] = u1; sy[wR + 190] = u2; sy[wR + 285] = u3; }
      // SW: 2 rows at tsw
      float a0 = sxb[aSwc], a1 = sxb[aSwc + 1];
      float b0 = sxb[aSwd], b1 = sxb[aSwd + 1];
      float p0, p1;
      if (power) { p0 = a0 + b1; p1 = b0 + a1; }
      else {
        ysw0 = fmaxf(ysw0 + sig * (a0 + b1 - 1.f), 0.f); p0 = ysw0;
        ysw1 = fmaxf(ysw1 + sig * (b0 + a1 - 1.f), 0.f); p1 = ysw1;
      }
      if (swAct) { sy[wS] = p0; sy[wS + 95] = p1; }
      // EQ row er (free dual, no projection)
      float ep = sxb[aEp], ecur = sxb[aEc];
      float exc = sxb[aEx], exd = sxb[aEx + 96];
      float dot = ecur - cEb * ep + cEm * (cET * exc + cDE * exd);
      float ev;
      if (power) ev = dot;
      else { yeq += sig * dot; ev = yeq; }
      if (eAct) sy[wE] = ev;
    }
    if (wid == 3) {
      // total-charge row: 0.25 * sum(x_bar_c) <= 1200
      float t0 = sxb[lane];
      float t1 = sxb[(lane < 32) ? 64 + lane : 95];
      float ssum = t0 + ((lane < 32) ? t1 : 0.f);
#pragma unroll
      for (int m = 32; m >= 1; m >>= 1) ssum += __shfl_xor(ssum, m, 64);
      if (lane == 0) {
        float wv;
        if (power) wv = 0.25f * ssum;
        else { ytc = fmaxf(ytc + sig * (0.25f * ssum - 1200.f), 0.f); wv = ytc; }
        sy[TCO] = wv;
      }
    }
  };

  // ============ power iteration for ||K||_2 ============
  for (int i = tid; i < NY; i += 256) sy[i] = 0.f;
  sxb[tid] = 1.f;
  if (tid < 224) sxb[256 + tid] = 1.f;
  if (tid < 8) sxb[480 + tid] = 0.f;
  __syncthreads();

  float lam2 = 1.f;
  for (int pit = 0; pit < PITER; ++pit) {
    phaseB(true);                     // sy = K v
    __syncthreads();
    float gA, gB;
    gatherA(gA, gB);                  // (K^T K v) per column
    if (!wBact) gB = 0.f;
    float part = gA * gA + gB * gB;
#pragma unroll
    for (int m = 32; m >= 1; m >>= 1) part += __shfl_xor(part, m, 64);
    if (lane == 0) s_red[wid] = part;
    __syncthreads();
    lam2 = sqrtf(s_red[0] + s_red[1] + s_red[2] + s_red[3]);
    float inv = 1.f / lam2;
    sxb[wxA] = gA * inv;
    if (wBact) sxb[wxB] = gB * inv;
    __syncthreads();
  }
  tau = (float)(0.9 / sqrt((double)lam2));
  sig = tau;

  // ============ PDHG ============
  for (int i = tid; i < NY; i += 256) sy[i] = 0.f;
  if (tid < 96)       qA = 0.25f * price[bi * 96 + tid];
  else if (tid < 192) qA = -0.25f * price[bi * 96 + (tid - 96)];
  xA = 0.f; xB = 0.f;
  __syncthreads();

#pragma unroll 1
  for (int it = 0; it < NITER; ++it) {
    float gA, gB;
    gatherA(gA, gB);
    float xa = xA - tau * (qA + gA);
    sxb[wxA] = 2.f * xa - xA;  xA = xa;
    float xb = xB - tau * gB;
    if (wBact) sxb[wxB] = 2.f * xb - xB;
    xB = xb;
    __syncthreads();
    phaseB(false);
    __syncthreads();
  }

  if (tid < 96)       out[bi * 96 + tid] = xA;
  else if (tid < 192) out[24576 + bi * 96 + (tid - 96)] = xA;
}

extern "C" void kernel_launch(void* const* d_in, const int* in_sizes, int n_in,
                              void* d_out, int out_size, void* d_ws, size_t ws_size,
                              hipStream_t stream) {
  const float* price = (const float*)d_in[0];
  float* outp = (float*)d_out;
  hipLaunchKernelGGL(lp_solve_kernel, dim3(256), dim3(256), 0, stream, price, outp);
}

// Round 4
// 315.775 us; speedup vs baseline: 1.8616x; 1.1360x over previous
//
#include <hip/hip_runtime.h>
#include <math.h>

// DiffDispatchLP: batched (256x) PDHG, 400 iters, one WG (8 waves, 512 thr)
// per batch item. Producer-side dual combining: phase B writes the exact
// per-column combinations phase A consumes (box 13 duals -> 5 combos,
// ramp 4 -> 2, min-dur own-sum shared by own/front terms). All LDS streams
// lane-stride-1; all addresses/masks hoisted before the iteration loop.

#define NITER 400
#define PITER 10

// combined-dual LDS layout (dword offsets)
#define BCO 0      // bC[96], bD[96]        (c/d box combos)
#define BYO 192    // bYC[96], bYD[96]      (yc/yd box combos)
#define BSO 384    // bS[96]                (soc box combo)
#define EQO 480    // eq[97]                (raw equality duals)
#define UCO 577    // uc[95], ud[95]        (ramp combos, row t at t-1)
#define SWO 767    // sw0[95], sw1[95]      (raw switch duals)
#define MDO 957    // md[v][k][95]: 957 + 285v + 95(k-1)  (raw, for "back")
#define MSO 1527   // mdS[v][97] own-sums (t=95,96 stay 0)
#define TCO 1721
#define NY  1722

__global__ __launch_bounds__(512, 1)
void lp_solve_kernel(const float* __restrict__ price, float* __restrict__ out) {
  __shared__ float sy[NY];     // combined duals / K*v combos
  __shared__ float sxb[480];   // x_bar SoA: c0 d96 yc192 yd288 soc384
  __shared__ float s_red[8];

  const int tid = threadIdx.x, lane = tid & 63, wid = tid >> 6, bi = blockIdx.x;
  const double ETA_D = sqrt(0.91);
  const float cET = (float)(-(ETA_D * 0.25));  // -ETA*DT
  const float cDE = (float)(0.25 / ETA_D);     // DT/ETA

  // ================= phase A precompute (one column per thread) =================
  const bool colAct = (tid < 480);
  const int  col = colAct ? tid : 479;
  const int  vty = col / 96;             // 0 c, 1 d, 2 yc, 3 yd, 4 soc
  const int  t   = col - 96 * vty;
  const int  v01 = (vty == 1 || vty == 3) ? 1 : 0;

  // cd body (wid 0..2)
  const int   aBcd = BCO + 96 * v01 + t;
  const int   aEqc = EQO + t;
  const int   aUm  = UCO + 95 * v01 + ((t >= 1) ? t - 1 : 0);
  const int   aUp  = UCO + 95 * v01 + ((t <= 94) ? t : 94);
  const float cmm  = (t >= 1) ? 1.f : 0.f;
  const float cpp  = (t <= 94) ? 1.f : 0.f;
  const float ce   = v01 ? cDE : cET;
  const float ctc  = v01 ? 0.f : 0.25f;

  // y body (wid 3..5)
  const int   aBY = BYO + 96 * v01 + t;
  const int   aS0 = SWO + 95 * v01 + ((t <= 94) ? t : 94);
  const int   aS1 = SWO + 95 * (1 - v01) + ((t >= 1) ? t - 1 : 0);
  const float cs0 = (t <= 94) ? 1.f : 0.f;
  const float cs1 = (t >= 1) ? 1.f : 0.f;
  const int   aMS = MSO + 97 * v01 + t;          // reads aMS, aMS+1
  const int   mvb = MDO + 285 * v01;
  const int   aK1 = mvb + ((t >= 1) ? t - 1 : 0);
  const int   aK2 = mvb + 95 + ((t >= 2) ? t - 2 : 0);
  const int   aK3 = mvb + 190 + ((t >= 3) ? t - 3 : 0);
  const float cb1 = (t >= 1) ? 1.f : 0.f;
  const float cb2 = (t >= 2) ? 1.f : 0.f;
  const float cb3 = (t >= 3) ? 1.f : 0.f;

  // soc body (wid 6..7)
  const int   aSE = EQO + t;                     // reads aSE, aSE+1
  const float ce1 = (t <= 94) ? -1.f : 1.f;
  const int   aBS = BSO + t;

  // ================= phase B precompute (row tasks per wave) =================
  // BOX: w0 t=lane; w1 lanes<32 t=64+lane
  const bool isBox = (wid == 0) || (wid == 1 && lane < 32);
  const int  tb = (wid == 0) ? lane : (64 + (lane & 31));
  // EQ: w1 lanes>=32 r=lane-32; w4 r=32+lane; w7 lane63 r=96
  const bool eqRun = (wid == 1) || (wid == 4) || (wid == 7);
  const bool eqAct = (wid == 1 && lane >= 32) || (wid == 4) || (wid == 7 && lane == 63);
  const int  er  = (wid == 1) ? ((lane >= 32) ? lane - 32 : 0)
                              : ((wid == 4) ? 32 + lane : 96);
  const int  ete = (er <= 95) ? er : 95;
  const int  aEp = 384 + ((ete >= 1) ? ete - 1 : 0);
  const int  aEc = 384 + ete;
  const int  aEx = ete;
  const float cEb = (er >= 1 && er <= 95) ? 1.f : 0.f;
  const float cEm = (er <= 95) ? 1.f : 0.f;
  // MD: w2 idx=lane, w3 idx=64+lane, w4 idx=128+lane (lane<62)
  const bool mdRun = (wid >= 2 && wid <= 4);
  const int  mi0 = ((wid - 2) << 6) + lane;
  const bool mdAct = mdRun && (mi0 < 190);
  const int  mi  = mdAct ? mi0 : 189;
  const int  mdv = (mi >= 95) ? 1 : 0;
  const int  mdt = mi - 95 * mdv;
  const int  mxb = 192 + 96 * mdv;
  const int  aMp = mxb + ((mdt >= 1) ? mdt - 1 : 0);
  const int  aMc = mxb + mdt;                    // reads aMc, aMc+1
  const int  aM2 = mxb + ((mdt <= 93) ? mdt + 2 : 95);
  const int  aM3 = mxb + ((mdt <= 92) ? mdt + 3 : 95);
  const float cMp = (mdt >= 1) ? 1.f : 0.f;
  const int  wMd = MDO + 285 * mdv + mdt;
  const bool vM1 = mdAct, vM2 = mdAct && (mdt <= 93), vM3 = mdAct && (mdt <= 92);
  const float cv1 = vM1 ? 1.f : 0.f, cv2 = vM2 ? 1.f : 0.f, cv3 = vM3 ? 1.f : 0.f;
  const int  wMS = MSO + 97 * mdv + mdt;
  // RAMP: w5 t=1+lane; w6 lanes<31 t=65+lane
  const bool rRun = (wid == 5) || (wid == 6);
  const bool rAct = (wid == 5) || (wid == 6 && lane < 31);
  const int  tr = (wid == 5) ? 1 + lane : (65 + ((lane < 31) ? lane : 30));
  // SW: w6 lanes>=31 t=lane-31; w7 lanes<62 t=33+lane
  const bool swRun = (wid >= 6);
  const bool swAct = (wid == 6 && lane >= 31) || (wid == 7 && lane < 62);
  const int  tsw = (wid == 6) ? ((lane >= 31) ? lane - 31 : 0)
                              : (33 + ((lane < 62) ? lane : 61));

  // ================= state =================
  float xA = 0.f, qA = 0.f;
  float yb0=0,yb1=0,yb2=0,yb3=0,yb4=0,yb5=0,yb6=0,yb7=0,yb8=0,yb9=0,yb10=0,yb11=0,yb12=0;
  float ym1=0, ym2=0, ym3=0, yr0=0, yr1=0, yr2=0, yr3=0, ysw0=0, ysw1=0, yeq=0, ytc=0;
  float tau = 0.f, sig = 0.f;

  auto gatherA = [&]() -> float {
    float g = 0.f;
    if (wid < 3) {
      float b  = sy[aBcd];
      float e  = sy[aEqc];
      float um = sy[aUm], up = sy[aUp];
      float tc = sy[TCO];
      g = b + ce * e + cmm * um - cpp * up + ctc * tc;
    } else if (wid < 6) {
      float bY = sy[aBY];
      float s0 = sy[aS0], s1 = sy[aS1];
      float m0 = sy[aMS], m1 = sy[aMS + 1];
      float k1 = sy[aK1], k2 = sy[aK2], k3 = sy[aK3];
      g = bY + cs0 * s0 + cs1 * s1 + (m0 - m1)
        - (cb1 * k1 + cb2 * k2 + cb3 * k3);
    } else {
      float bS = sy[aBS];
      float e0 = sy[aSE], e1 = sy[aSE + 1];
      g = bS + e0 + ce1 * e1;
    }
    return g;
  };

  auto phaseB = [&](bool power) {
    if (wid <= 1) {  // BOX
      float c_ = sxb[tb], d_ = sxb[96 + tb];
      float yc_ = sxb[192 + tb], yd_ = sxb[288 + tb], s_ = sxb[384 + tb];
      float v0,v1,v2,v3,v4,v5,v6,v7,v8,v9,v10,v11,v12;
      if (power) {
        v0=c_; v1=d_; v2=-c_; v3=-d_; v4=-yc_; v5=yc_; v6=-yd_; v7=yd_;
        v8=-s_; v9=s_; v10=yc_+yd_; v11=c_-195.f*yc_; v12=d_-195.f*yd_;
      } else {
        yb0  = fmaxf(yb0  + sig*(c_  - 195.f), 0.f);      v0 = yb0;
        yb1  = fmaxf(yb1  + sig*(d_  - 195.f), 0.f);      v1 = yb1;
        yb2  = fmaxf(yb2  - sig*c_,            0.f);      v2 = yb2;
        yb3  = fmaxf(yb3  - sig*d_,            0.f);      v3 = yb3;
        yb4  = fmaxf(yb4  - sig*yc_,           0.f);      v4 = yb4;
        yb5  = fmaxf(yb5  + sig*(yc_ - 1.f),   0.f);      v5 = yb5;
        yb6  = fmaxf(yb6  - sig*yd_,           0.f);      v6 = yb6;
        yb7  = fmaxf(yb7  + sig*(yd_ - 1.f),   0.f);      v7 = yb7;
        yb8  = fmaxf(yb8  - sig*s_,            0.f);      v8 = yb8;
        yb9  = fmaxf(yb9  + sig*(s_ - 800.f),  0.f);      v9 = yb9;
        yb10 = fmaxf(yb10 + sig*(yc_ + yd_ - 1.f), 0.f);  v10 = yb10;
        yb11 = fmaxf(yb11 + sig*(c_ - 195.f*yc_), 0.f);   v11 = yb11;
        yb12 = fmaxf(yb12 + sig*(d_ - 195.f*yd_), 0.f);   v12 = yb12;
      }
      if (isBox) {
        sy[BCO + tb]      = v0 - v2 + v11;
        sy[BCO + 96 + tb] = v1 - v3 + v12;
        sy[BYO + tb]      = -v4 + v5 + v10 - 195.f * v11;
        sy[BYO + 96 + tb] = -v6 + v7 + v10 - 195.f * v12;
        sy[BSO + tb]      = -v8 + v9;
      }
    }
    if (mdRun) {  // MIN-DURATION (3 rows + own-sum)
      float mp = sxb[aMp];
      float mc = sxb[aMc], m1v = sxb[aMc + 1];
      float m2v = sxb[aM2], m3v = sxb[aM3];
      float base = mc - cMp * mp;
      float d1 = base - m1v, d2 = base - m2v, d3 = base - m3v;
      float o1, o2, o3;
      if (power) { o1 = d1; o2 = d2; o3 = d3; }
      else {
        ym1 = fmaxf(ym1 + sig * d1, 0.f); o1 = ym1;
        ym2 = fmaxf(ym2 + sig * d2, 0.f); o2 = ym2;
        ym3 = fmaxf(ym3 + sig * d3, 0.f); o3 = ym3;
      }
      if (vM1) sy[wMd]       = o1;
      if (vM2) sy[wMd + 95]  = o2;
      if (vM3) sy[wMd + 190] = o3;
      if (mdAct) sy[wMS] = cv1 * o1 + cv2 * o2 + cv3 * o3;
    }
    if (rRun) {  // RAMP (4 rows -> 2 combos)
      float rcm = sxb[tr - 1], rc0 = sxb[tr];
      float rdm = sxb[96 + tr - 1], rd0 = sxb[96 + tr];
      float u0, u1, u2, u3;
      if (power) { u0 = rc0 - rcm; u1 = rcm - rc0; u2 = rd0 - rdm; u3 = rdm - rd0; }
      else {
        yr0 = fmaxf(yr0 + sig * (rc0 - rcm - 65.f), 0.f); u0 = yr0;
        yr1 = fmaxf(yr1 + sig * (rcm - rc0 - 65.f), 0.f); u1 = yr1;
        yr2 = fmaxf(yr2 + sig * (rd0 - rdm - 65.f), 0.f); u2 = yr2;
        yr3 = fmaxf(yr3 + sig * (rdm - rd0 - 65.f), 0.f); u3 = yr3;
      }
      if (rAct) { sy[UCO + tr - 1] = u0 - u1; sy[UCO + 95 + tr - 1] = u2 - u3; }
    }
    if (swRun) {  // SWITCH (2 raw rows)
      float a0 = sxb[192 + tsw], a1 = sxb[192 + tsw + 1];
      float b0 = sxb[288 + tsw], b1 = sxb[288 + tsw + 1];
      float p0, p1;
      if (power) { p0 = a0 + b1; p1 = b0 + a1; }
      else {
        ysw0 = fmaxf(ysw0 + sig * (a0 + b1 - 1.f), 0.f); p0 = ysw0;
        ysw1 = fmaxf(ysw1 + sig * (b0 + a1 - 1.f), 0.f); p1 = ysw1;
      }
      if (swAct) { sy[SWO + tsw] = p0; sy[SWO + 95 + tsw] = p1; }
    }
    if (eqRun) {  // EQUALITY (raw, free dual)
      float ep = sxb[aEp], ecur = sxb[aEc];
      float exc = sxb[aEx], exd = sxb[aEx + 96];
      float dot = ecur - cEb * ep + cEm * (cET * exc + cDE * exd);
      float ev;
      if (power) ev = dot;
      else { yeq += sig * dot; ev = yeq; }
      if (eqAct) sy[EQO + er] = ev;
    }
    if (wid == 7) {  // TOTAL-CHARGE: 0.25 * sum(c_bar) <= 1200
      float ssum = sxb[lane] + ((lane < 32) ? sxb[64 + lane] : 0.f);
#pragma unroll
      for (int m = 32; m >= 1; m >>= 1) ssum += __shfl_xor(ssum, m, 64);
      if (lane == 0) {
        float wv;
        if (power) wv = 0.25f * ssum;
        else { ytc = fmaxf(ytc + sig * (0.25f * ssum - 1200.f), 0.f); wv = ytc; }
        sy[TCO] = wv;
      }
    }
  };

  // ================= power iteration: ||K||_2 =================
  for (int i = tid; i < NY; i += 512) sy[i] = 0.f;
  if (colAct) sxb[tid] = 1.f;
  __syncthreads();

  float lam2 = 1.f;
  for (int pit = 0; pit < PITER; ++pit) {
    phaseB(true);                          // sy = combined(K v)
    __syncthreads();
    float gA = gatherA();                  // (K^T K v) per column
    if (!colAct) gA = 0.f;
    float part = gA * gA;
#pragma unroll
    for (int m = 32; m >= 1; m >>= 1) part += __shfl_xor(part, m, 64);
    if (lane == 0) s_red[wid] = part;
    __syncthreads();
    lam2 = sqrtf(s_red[0] + s_red[1] + s_red[2] + s_red[3]
               + s_red[4] + s_red[5] + s_red[6] + s_red[7]);
    float inv = 1.f / lam2;
    if (colAct) sxb[tid] = gA * inv;
    __syncthreads();
  }
  tau = (float)(0.9 / sqrt((double)lam2));
  sig = tau;

  // ================= PDHG =================
  for (int i = tid; i < NY; i += 512) sy[i] = 0.f;
  if (tid < 96)       qA =  0.25f * price[bi * 96 + tid];
  else if (tid < 192) qA = -0.25f * price[bi * 96 + (tid - 96)];
  __syncthreads();

#pragma unroll 1
  for (int it = 0; it < NITER; ++it) {
    float gA = gatherA();
    if (colAct) {
      float xa = xA - tau * (qA + gA);
      sxb[tid] = 2.f * xa - xA;
      xA = xa;
    }
    __syncthreads();
    phaseB(false);
    __syncthreads();
  }

  if (tid < 96)       out[bi * 96 + tid] = xA;
  else if (tid < 192) out[24576 + bi * 96 + (tid - 96)] = xA;
}

extern "C" void kernel_launch(void* const* d_in, const int* in_sizes, int n_in,
                              void* d_out, int out_size, void* d_ws, size_t ws_size,
                              hipStream_t stream) {
  const float* price = (const float*)d_in[0];
  float* outp = (float*)d_out;
  hipLaunchKernelGGL(lp_solve_kernel, dim3(256), dim3(512), 0, stream, price, outp);
}

// Round 5
// 308.820 us; speedup vs baseline: 1.9035x; 1.0225x over previous
//
#include <hip/hip_runtime.h>
#include <math.h>

// DiffDispatchLP: batched (256x) PDHG, 400 iters, one WG (8 waves) per item.
// All LDS arrays padded with zero guards so every access is base + constant
// immediate offset (no per-iteration address math, no boundary masks).
// Total-charge reduction isolated on wave 7 to overlap its shfl chain.
//
// sy layout (dwords), each region = [4 guard][data][guard...] stride 104:
//   VB[v] at 624v: MD1@0 MD2@104 MD3@208 MS@312 BY@416 SW@520   (v=0,1)
//   EQ@1248  BS@1352  BCD@1456 (c@1456,d@1560)  UC@1664 (uc,ud)  TC@1872
// sxb layout: C@0 D@104 YC@208 YD@312 S@416  (slot = region + 4 + t)

#define NITER 400
#define PITER 10
#define NY 1874
#define NX 520

__global__ __launch_bounds__(512, 1)
void lp_solve_kernel(const float* __restrict__ price, float* __restrict__ out) {
  __shared__ float sy[NY];
  __shared__ float sxb[NX];
  __shared__ float s_red[8];

  const int tid = threadIdx.x, lane = tid & 63, wid = tid >> 6, bi = blockIdx.x;
  const double ETA_D = sqrt(0.91);
  const float cET = (float)(-(ETA_D * 0.25));  // -ETA*DT
  const float cDE = (float)(0.25 / ETA_D);     // DT/ETA

  // ================= phase A per-thread constants =================
  const bool colAct = (tid < 480);
  const int col = colAct ? tid : 479;
  const int vty = col / 96;            // 0 c, 1 d, 2 yc, 3 yd, 4 soc
  const int t = col - 96 * vty;
  const int wX = 104 * vty + 4 + t;    // x_bar write slot

  // cd body (wid 0..2)
  const int v01 = vty & 1;
  const int aBC = 1460 + 104 * v01 + t;   // bC/bD combo
  const int aEQ = 1252 + t;               // eq[t]
  const int aUM = 1667 + 104 * v01 + t;   // uc[t-1] (t=0 -> guard)
  const float ce = v01 ? cDE : cET;
  const float ctc = v01 ? 0.f : 0.25f;

  // y body (wid 3..5): bases into VB[v], VB[1-v]
  const int yv = (vty >= 2) ? (vty - 2) : 0;
  const int bv = 624 * yv + t;
  const int bw = 624 * (1 - yv) + t;

  // soc body (wid 6..7)
  const float ce1 = (t <= 94) ? -1.f : 1.f;
  const int aBS = 1356 + t;

  // ================= phase B per-thread constants =================
  // BOX: w0 t=lane; w1 lanes<32 t=64+lane
  const int tb = (wid == 0) ? lane : (64 + (lane & 31));
  const bool isBox = (wid == 0) || (wid == 1 && lane < 32);
  // EQ: w1 lanes>=32 r=0..31; w5 all r=32..95; w7 lane32 r=96
  int er; bool eqRun, eqAct;
  if (wid == 1)      { er = (lane >= 32) ? lane - 32 : 0; eqRun = true; eqAct = (lane >= 32); }
  else if (wid == 5) { er = 32 + lane; eqRun = true; eqAct = true; }
  else if (wid == 7) { er = 96; eqRun = true; eqAct = (lane == 32); }
  else               { er = 0; eqRun = false; eqAct = false; }
  const float cEb = (er == 96) ? -1.f : 1.f;  // r=96: dot = +s[95] via guard at s[96]
  // MD: w2 i=lane, w3 i=64+lane, w4 i=128+lane (i<190)
  const bool mdRun = (wid >= 2) && (wid <= 4);
  const int mi0 = ((wid - 2) << 6) + lane;
  const bool mdAct = mdRun && (mi0 < 190);
  const int mi = mdAct ? mi0 : 189;
  const int mv = (mi >= 95) ? 1 : 0;
  const int mt = mi - 95 * mv;
  const int mx = 104 * (2 + mv) + mt;   // sxb y_v base
  const int mw = 624 * mv + mt;         // sy VB[v] write base
  const float cv2 = (mt <= 93) ? 1.f : 0.f;
  const float cv3 = (mt <= 92) ? 1.f : 0.f;
  // RAMP: w5 t=1..64 (double-duty with eq); w6 lanes<31 t=65..95
  const bool rRun = (wid == 5) || (wid == 6);
  const bool rAct = (wid == 5) || (wid == 6 && lane < 31);
  const int rt = (wid == 5) ? (1 + lane) : (65 + ((lane < 31) ? lane : 30));
  // SW: w6 all t=0..63; w7 lanes<31 t=64..94
  const bool sRun = (wid >= 6);
  const bool sAct = (wid == 6) || (wid == 7 && lane < 31);
  const int st = (wid == 6) ? lane : (64 + ((lane < 31) ? lane : 30));

  // ================= state =================
  float xA = 0.f, qA = 0.f;
  float yb0=0,yb1=0,yb2=0,yb3=0,yb4=0,yb5=0,yb6=0,yb7=0,yb8=0,yb9=0,yb10=0,yb11=0,yb12=0;
  float ym1=0, ym2=0, ym3=0, yr0=0, yr1=0, yr2=0, yr3=0, ysw0=0, ysw1=0, yeq=0, ytc=0;

  auto gatherA = [&]() -> float {
    if (wid < 3) {
      float b = sy[aBC], e = sy[aEQ];
      float um = sy[aUM], up = sy[aUM + 1];
      float tc = sy[1872];
      return b + ce * e + um - up + ctc * tc;
    } else if (wid < 6) {
      float k1 = sy[bv + 3], k2 = sy[bv + 106], k3 = sy[bv + 209];
      float m0 = sy[bv + 316], m1 = sy[bv + 317];
      float bY = sy[bv + 420], s0 = sy[bv + 524], s1 = sy[bw + 523];
      return bY + s0 + s1 + (m0 - m1) - (k1 + k2 + k3);
    } else {
      float e0 = sy[aEQ], e1 = sy[aEQ + 1], bS = sy[aBS];
      return bS + e0 + ce1 * e1;
    }
  };

  auto phaseB = [&](bool power) {
    if (wid <= 1) {  // BOX: 13 rows at tb -> 5 combos
      float c_ = sxb[4 + tb], d_ = sxb[108 + tb];
      float yc_ = sxb[212 + tb], yd_ = sxb[316 + tb], s_ = sxb[420 + tb];
      float v0,v1,v2,v3,v4,v5,v6,v7,v8,v9,v10,v11,v12;
      if (power) {
        v0=c_; v1=d_; v2=-c_; v3=-d_; v4=-yc_; v5=yc_; v6=-yd_; v7=yd_;
        v8=-s_; v9=s_; v10=yc_+yd_; v11=c_-195.f*yc_; v12=d_-195.f*yd_;
      } else {
        float sig = qA;  // unused alias suppressor
        (void)sig;
      }
      if (!power) {
        // sig passed via captured tauSig below
      }
      (void)v0;
      // (body continues in phaseB2 to keep sig capture clean)
      if (power) {
        if (isBox) {
          sy[1460 + tb] = v0 - v2 + v11;
          sy[1564 + tb] = v1 - v3 + v12;
          sy[420 + tb]  = -v4 + v5 + v10 - 195.f * v11;
          sy[1044 + tb] = -v6 + v7 + v10 - 195.f * v12;
          sy[1356 + tb] = -v8 + v9;
        }
      }
    }
  };
  (void)phaseB;

  // full phase B with sigma (single implementation; power selects raw dots)
  float tauv = 0.f, sigv = 0.f;
  auto phaseBfull = [&](bool power) {
    const float sig = sigv;
    if (wid <= 1) {  // BOX
      float c_ = sxb[4 + tb], d_ = sxb[108 + tb];
      float yc_ = sxb[212 + tb], yd_ = sxb[316 + tb], s_ = sxb[420 + tb];
      float v0,v1,v2,v3,v4,v5,v6,v7,v8,v9,v10,v11,v12;
      if (power) {
        v0=c_; v1=d_; v2=-c_; v3=-d_; v4=-yc_; v5=yc_; v6=-yd_; v7=yd_;
        v8=-s_; v9=s_; v10=yc_+yd_; v11=c_-195.f*yc_; v12=d_-195.f*yd_;
      } else {
        yb0  = fmaxf(yb0  + sig*(c_  - 195.f), 0.f);      v0 = yb0;
        yb1  = fmaxf(yb1  + sig*(d_  - 195.f), 0.f);      v1 = yb1;
        yb2  = fmaxf(yb2  - sig*c_,            0.f);      v2 = yb2;
        yb3  = fmaxf(yb3  - sig*d_,            0.f);      v3 = yb3;
        yb4  = fmaxf(yb4  - sig*yc_,           0.f);      v4 = yb4;
        yb5  = fmaxf(yb5  + sig*(yc_ - 1.f),   0.f);      v5 = yb5;
        yb6  = fmaxf(yb6  - sig*yd_,           0.f);      v6 = yb6;
        yb7  = fmaxf(yb7  + sig*(yd_ - 1.f),   0.f);      v7 = yb7;
        yb8  = fmaxf(yb8  - sig*s_,            0.f);      v8 = yb8;
        yb9  = fmaxf(yb9  + sig*(s_ - 800.f),  0.f);      v9 = yb9;
        yb10 = fmaxf(yb10 + sig*(yc_ + yd_ - 1.f), 0.f);  v10 = yb10;
        yb11 = fmaxf(yb11 + sig*(c_ - 195.f*yc_), 0.f);   v11 = yb11;
        yb12 = fmaxf(yb12 + sig*(d_ - 195.f*yd_), 0.f);   v12 = yb12;
      }
      if (isBox) {
        sy[1460 + tb] = v0 - v2 + v11;                     // bC
        sy[1564 + tb] = v1 - v3 + v12;                     // bD
        sy[420 + tb]  = -v4 + v5 + v10 - 195.f * v11;      // bYC
        sy[1044 + tb] = -v6 + v7 + v10 - 195.f * v12;      // bYD
        sy[1356 + tb] = -v8 + v9;                          // bS
      }
    }
    if (mdRun) {  // MIN-DURATION: rows (v, k=1..3, mt) + own-sum
      float mp = sxb[mx + 3];                // y_v[t-1] (guard at t=0)
      float mc = sxb[mx + 4], m1v = sxb[mx + 5];
      float m2v = sxb[mx + 6], m3v = sxb[mx + 7];
      float base = mc - mp;
      float d1 = base - m1v, d2 = base - m2v, d3 = base - m3v;
      float o1, o2, o3;
      if (power) { o1 = d1; o2 = d2; o3 = d3; }
      else {
        ym1 = fmaxf(ym1 + sig * d1, 0.f); o1 = ym1;
        ym2 = fmaxf(ym2 + sig * d2, 0.f); o2 = ym2;
        ym3 = fmaxf(ym3 + sig * d3, 0.f); o3 = ym3;
      }
      if (mdAct) {
        sy[mw + 4]   = o1;
        sy[mw + 108] = o2;
        sy[mw + 212] = o3;
        sy[mw + 316] = o1 + cv2 * o2 + cv3 * o3;  // own-sum (valid rows only)
      }
    }
    if (rRun) {  // RAMP: 4 rows -> 2 combos
      float rcm = sxb[3 + rt], rc0 = sxb[4 + rt];
      float rdm = sxb[107 + rt], rd0 = sxb[108 + rt];
      float u0, u1, u2, u3;
      if (power) { u0 = rc0 - rcm; u1 = rcm - rc0; u2 = rd0 - rdm; u3 = rdm - rd0; }
      else {
        yr0 = fmaxf(yr0 + sig * (rc0 - rcm - 65.f), 0.f); u0 = yr0;
        yr1 = fmaxf(yr1 + sig * (rcm - rc0 - 65.f), 0.f); u1 = yr1;
        yr2 = fmaxf(yr2 + sig * (rd0 - rdm - 65.f), 0.f); u2 = yr2;
        yr3 = fmaxf(yr3 + sig * (rdm - rd0 - 65.f), 0.f); u3 = yr3;
      }
      if (rAct) { sy[1667 + rt] = u0 - u1; sy[1771 + rt] = u2 - u3; }
    }
    if (sRun) {  // SWITCH: 2 raw rows
      float a0 = sxb[212 + st], a1 = sxb[213 + st];
      float b0 = sxb[316 + st], b1 = sxb[317 + st];
      float p0, p1;
      if (power) { p0 = a0 + b1; p1 = b0 + a1; }
      else {
        ysw0 = fmaxf(ysw0 + sig * (a0 + b1 - 1.f), 0.f); p0 = ysw0;
        ysw1 = fmaxf(ysw1 + sig * (b0 + a1 - 1.f), 0.f); p1 = ysw1;
      }
      if (sAct) { sy[524 + st] = p0; sy[1148 + st] = p1; }
    }
    if (eqRun) {  // EQUALITY (free dual); r=96 handled by guards + cEb=-1
      float ep = sxb[419 + er], ecur = sxb[420 + er];
      float exc = sxb[4 + er], exd = sxb[108 + er];
      float dot = ecur - cEb * ep + cET * exc + cDE * exd;
      float ev;
      if (power) ev = dot;
      else { yeq += sig * dot; ev = yeq; }
      if (eqAct) sy[1252 + er] = ev;
    }
    if (wid == 7) {  // TOTAL-CHARGE (dedicated wave; chain overlaps others)
      float ssum = sxb[4 + lane] + ((lane < 32) ? sxb[68 + lane] : 0.f);
#pragma unroll
      for (int m = 32; m >= 1; m >>= 1) ssum += __shfl_xor(ssum, m, 64);
      if (lane == 0) {
        float wv;
        if (power) wv = 0.25f * ssum;
        else { ytc = fmaxf(ytc + sig * (0.25f * ssum - 1200.f), 0.f); wv = ytc; }
        sy[1872] = wv;
      }
    }
  };

  // ================= power iteration: ||K||_2 =================
  for (int i = tid; i < NY; i += 512) sy[i] = 0.f;
  for (int i = tid; i < NX; i += 512) sxb[i] = 0.f;
  __syncthreads();
  if (colAct) sxb[wX] = 1.f;
  __syncthreads();

  float lam2 = 1.f;
  for (int pit = 0; pit < PITER; ++pit) {
    phaseBfull(true);                      // sy = combined(K v)
    __syncthreads();
    float gA = gatherA();                  // (K^T K v) per column
    if (!colAct) gA = 0.f;
    float part = gA * gA;
#pragma unroll
    for (int m = 32; m >= 1; m >>= 1) part += __shfl_xor(part, m, 64);
    if (lane == 0) s_red[wid] = part;
    __syncthreads();
    lam2 = sqrtf(s_red[0] + s_red[1] + s_red[2] + s_red[3]
               + s_red[4] + s_red[5] + s_red[6] + s_red[7]);
    float inv = 1.f / lam2;
    if (colAct) sxb[wX] = gA * inv;
    __syncthreads();
  }
  tauv = (float)(0.9 / sqrt((double)lam2));
  sigv = tauv;

  // ================= PDHG =================
  for (int i = tid; i < NY; i += 512) sy[i] = 0.f;
  if (tid < 96)       qA =  0.25f * price[bi * 96 + tid];
  else if (tid < 192) qA = -0.25f * price[bi * 96 + (tid - 96)];
  __syncthreads();

#pragma unroll 1
  for (int it = 0; it < NITER; ++it) {
    float gA = gatherA();
    if (colAct) {
      float xa = xA - tauv * (qA + gA);
      sxb[wX] = 2.f * xa - xA;
      xA = xa;
    }
    __syncthreads();
    phaseBfull(false);
    __syncthreads();
  }

  // output: c then d, each (256,96)
  if (tid < 96)       out[bi * 96 + tid] = xA;
  else if (tid < 192) out[24576 + bi * 96 + (tid - 96)] = xA;
}

extern "C" void kernel_launch(void* const* d_in, const int* in_sizes, int n_in,
                              void* d_out, int out_size, void* d_ws, size_t ws_size,
                              hipStream_t stream) {
  const float* price = (const float*)d_in[0];
  float* outp = (float*)d_out;
  hipLaunchKernelGGL(lp_solve_kernel, dim3(256), dim3(512), 0, stream, price, outp);
}